// Round 1
// baseline (205.742 us; speedup 1.0000x reference)
//
#include <hip/hip_runtime.h>

// Windowed MHA, B=16 C=128 H=W=128, WINDOW=64, heads=4, d=32.
// One block per (batch, window): 4096 blocks x 256 threads (4 waves; wave = head).
// bf16 MFMA 16x16x32, fp32 accumulate. All LDS tiles XOR-swizzled vs bank conflicts.

typedef __attribute__((ext_vector_type(8))) short bf16x8;
typedef __attribute__((ext_vector_type(4))) float f32x4;

__device__ __forceinline__ ushort f2bf(float f) {
    unsigned u = __float_as_uint(f);
    u += 0x7FFF + ((u >> 16) & 1);          // RNE
    return (ushort)(u >> 16);
}

__global__ void wconv(const float* __restrict__ Wq, const float* __restrict__ Wk,
                      const float* __restrict__ Wv, ushort* __restrict__ out) {
    int i = blockIdx.x * 256 + threadIdx.x;        // 16384 per matrix
    out[i]         = f2bf(Wq[i]);
    out[16384 + i] = f2bf(Wk[i]);
    out[32768 + i] = f2bf(Wv[i]);
}

__global__ __launch_bounds__(256)
void attn_win(const float* __restrict__ x, const ushort* __restrict__ wbf,
              const float* __restrict__ bq, const float* __restrict__ bk,
              const float* __restrict__ bv, const float* __restrict__ Bb,
              float* __restrict__ out) {
    __shared__ __align__(16) char smem[65536];
    // layout: [0,16K) sX  [16K,32K) sQ  [32K,48K) sK  [48K,64K) sVt
    // aliases after phases die: sP(4x8K probs) on [16K,48K); sOut(32K f32) on [16K,48K)
    char* sX  = smem;
    char* sQ  = smem + 16384;
    char* sK  = smem + 32768;
    char* sVt = smem + 49152;
    char* sP  = smem + 16384;
    char* sOut = smem + 16384;

    const int tid = threadIdx.x;
    const int w = tid >> 6;          // wave = head
    const int l = tid & 63;
    const int lr = l & 15;           // lane % 16
    const int lg = l >> 4;           // lane / 16 (0..3)
    const int blk = blockIdx.x;
    const int b = blk >> 8, n = blk & 255;
    const long xbase = (long)b * 128 * 16384 + n * 64;

    // ---- load X window (64 tok x 128 ch), fp32 -> bf16 into sX[t][c] swizzled ----
    for (int it = 0; it < 8; ++it) {
        int f4i = it * 256 + tid;            // 2048 float4 total
        int c = f4i >> 4, t4 = f4i & 15;
        float4 v = *(const float4*)(x + xbase + (long)c * 16384 + t4 * 4);
        float vv[4] = {v.x, v.y, v.z, v.w};
        #pragma unroll
        for (int jj = 0; jj < 4; ++jj) {
            int t = t4 * 4 + jj;
            *(ushort*)(sX + t * 256 + ((c * 2) ^ ((t & 7) << 4))) = f2bf(vv[jj]);
        }
    }
    __syncthreads();   // B1

    // ---- A-fragments of X (shared across the 3 projections) ----
    bf16x8 aX[4][4];
    #pragma unroll
    for (int tm = 0; tm < 4; ++tm) {
        int row = 16 * tm + lr;
        #pragma unroll
        for (int kk = 0; kk < 4; ++kk) {
            int colb = (8 * lg + 32 * kk) * 2;
            aX[tm][kk] = *(const bf16x8*)(sX + row * 256 + (colb ^ ((row & 7) << 4)));
        }
    }

    // ---- Q,K,V projections: out[t][o] = sum_c X[t][c]*W[o][c] + b[o] ----
    const float* biases[3] = {bq, bk, bv};
    #pragma unroll
    for (int p = 0; p < 3; ++p) {
        const ushort* wp = wbf + p * 16384;
        bf16x8 bW[2][4];
        #pragma unroll
        for (int tn = 0; tn < 2; ++tn) {
            int orow = 32 * w + 16 * tn + lr;
            #pragma unroll
            for (int kk = 0; kk < 4; ++kk)
                bW[tn][kk] = *(const bf16x8*)(wp + orow * 128 + 8 * lg + 32 * kk);
        }
        f32x4 acc[4][2];
        #pragma unroll
        for (int tn = 0; tn < 2; ++tn) {
            float bias = biases[p][32 * w + 16 * tn + lr];
            #pragma unroll
            for (int tm = 0; tm < 4; ++tm)
                acc[tm][tn] = (f32x4){bias, bias, bias, bias};
        }
        #pragma unroll
        for (int kk = 0; kk < 4; ++kk)
            #pragma unroll
            for (int tm = 0; tm < 4; ++tm)
                #pragma unroll
                for (int tn = 0; tn < 2; ++tn)
                    acc[tm][tn] = __builtin_amdgcn_mfma_f32_16x16x32_bf16(
                        aX[tm][kk], bW[tn][kk], acc[tm][tn], 0, 0, 0);
        // epilogue: D layout row=16tm+4lg+r, col=32w+16tn+lr
        if (p < 2) {
            char* dst = (p == 0) ? sQ : sK;
            #pragma unroll
            for (int tm = 0; tm < 4; ++tm)
                #pragma unroll
                for (int tn = 0; tn < 2; ++tn)
                    #pragma unroll
                    for (int r = 0; r < 4; ++r) {
                        int row = 16 * tm + 4 * lg + r;
                        int col = 32 * w + 16 * tn + lr;
                        *(ushort*)(dst + row * 256 + ((col * 2) ^ ((row & 7) << 4)))
                            = f2bf(acc[tm][tn][r]);
                    }
        } else {
            // V stored transposed: sVt[c][token], rowbytes 128
            #pragma unroll
            for (int tm = 0; tm < 4; ++tm)
                #pragma unroll
                for (int tn = 0; tn < 2; ++tn)
                    #pragma unroll
                    for (int r = 0; r < 4; ++r) {
                        int crow = 32 * w + 16 * tn + lr;
                        int tok = 16 * tm + 4 * lg + r;
                        *(ushort*)(sVt + crow * 128 + ((tok * 2) ^ ((crow & 7) << 4)))
                            = f2bf(acc[tm][tn][r]);
                    }
        }
    }
    __syncthreads();   // B2

    // ---- scores = Q . K^T for head w: M=64 q, N=64 k, K=32 ----
    bf16x8 aQ[4], bK[4];
    #pragma unroll
    for (int tm = 0; tm < 4; ++tm) {
        int row = 16 * tm + lr;
        int colb = (32 * w + 8 * lg) * 2;
        aQ[tm] = *(const bf16x8*)(sQ + row * 256 + (colb ^ ((row & 7) << 4)));
    }
    #pragma unroll
    for (int tn = 0; tn < 4; ++tn) {
        int tok = 16 * tn + lr;
        int colb = (32 * w + 8 * lg) * 2;
        bK[tn] = *(const bf16x8*)(sK + tok * 256 + (colb ^ ((tok & 7) << 4)));
    }
    f32x4 sc[4][4];
    #pragma unroll
    for (int tm = 0; tm < 4; ++tm)
        #pragma unroll
        for (int tn = 0; tn < 4; ++tn) {
            sc[tm][tn] = (f32x4){0.f, 0.f, 0.f, 0.f};
            sc[tm][tn] = __builtin_amdgcn_mfma_f32_16x16x32_bf16(
                aQ[tm], bK[tn], sc[tm][tn], 0, 0, 0);
        }

    // ---- softmax (registers). row q = 16tm+4lg+r spans 16 lanes (l&15) x 4 tn ----
    const float scale = 0.17677669529663687f;   // 1/sqrt(32)
    #pragma unroll
    for (int tm = 0; tm < 4; ++tm)
        #pragma unroll
        for (int tn = 0; tn < 4; ++tn)
            #pragma unroll
            for (int r = 0; r < 4; ++r) {
                int q = 16 * tm + 4 * lg + r;
                int k = 16 * tn + lr;
                sc[tm][tn][r] = sc[tm][tn][r] * scale + Bb[q * 64 + k];
            }
    float rsum[4][4];
    #pragma unroll
    for (int tm = 0; tm < 4; ++tm)
        #pragma unroll
        for (int r = 0; r < 4; ++r) {
            float m = fmaxf(fmaxf(sc[tm][0][r], sc[tm][1][r]),
                            fmaxf(sc[tm][2][r], sc[tm][3][r]));
            m = fmaxf(m, __shfl_xor(m, 1));
            m = fmaxf(m, __shfl_xor(m, 2));
            m = fmaxf(m, __shfl_xor(m, 4));
            m = fmaxf(m, __shfl_xor(m, 8));
            float s = 0.f;
            #pragma unroll
            for (int tn = 0; tn < 4; ++tn) {
                float e = exp2f((sc[tm][tn][r] - m) * 1.4426950408889634f);
                sc[tm][tn][r] = e;
                s += e;
            }
            s += __shfl_xor(s, 1);
            s += __shfl_xor(s, 2);
            s += __shfl_xor(s, 4);
            s += __shfl_xor(s, 8);
            rsum[tm][r] = 1.0f / s;   // folded into PV epilogue
        }
    __syncthreads();   // B3: all waves done reading sQ/sK before sP overwrites them

    // ---- write probs (unnormalized, <=1) bf16 to per-wave sP [64][64] ----
    char* sPw = sP + w * 8192;
    #pragma unroll
    for (int tm = 0; tm < 4; ++tm)
        #pragma unroll
        for (int tn = 0; tn < 4; ++tn)
            #pragma unroll
            for (int r = 0; r < 4; ++r) {
                int q = 16 * tm + 4 * lg + r;
                int k = 16 * tn + lr;
                *(ushort*)(sPw + q * 128 + ((k * 2) ^ ((q & 7) << 4))) = f2bf(sc[tm][tn][r]);
            }
    __syncthreads();   // B4

    // ---- out = P . V : M=64 q, N=32 d, K=64 keys ----
    f32x4 o[4][2];
    #pragma unroll
    for (int tm = 0; tm < 4; ++tm)
        #pragma unroll
        for (int tn = 0; tn < 2; ++tn)
            o[tm][tn] = (f32x4){0.f, 0.f, 0.f, 0.f};
    #pragma unroll
    for (int kk = 0; kk < 2; ++kk) {
        bf16x8 aP[4], bV[2];
        #pragma unroll
        for (int tm = 0; tm < 4; ++tm) {
            int q = 16 * tm + lr;
            int colb = (32 * kk + 8 * lg) * 2;
            aP[tm] = *(const bf16x8*)(sPw + q * 128 + (colb ^ ((q & 7) << 4)));
        }
        #pragma unroll
        for (int tn = 0; tn < 2; ++tn) {
            int cc = 32 * w + 16 * tn + lr;
            int colb = (32 * kk + 8 * lg) * 2;
            bV[tn] = *(const bf16x8*)(sVt + cc * 128 + (colb ^ ((cc & 7) << 4)));
        }
        #pragma unroll
        for (int tm = 0; tm < 4; ++tm)
            #pragma unroll
            for (int tn = 0; tn < 2; ++tn)
                o[tm][tn] = __builtin_amdgcn_mfma_f32_16x16x32_bf16(
                    aP[tm], bV[tn], o[tm][tn], 0, 0, 0);
    }
    __syncthreads();   // B5: sP reads done before sOut overwrites region

    // ---- stage output c-major (f32) for coalesced global writes ----
    #pragma unroll
    for (int tm = 0; tm < 4; ++tm)
        #pragma unroll
        for (int tn = 0; tn < 2; ++tn)
            #pragma unroll
            for (int r = 0; r < 4; ++r) {
                int cc = 32 * w + 16 * tn + lr;
                int tok = 16 * tm + 4 * lg + r;
                *(float*)(sOut + cc * 256 + ((tok * 4) ^ ((cc & 7) << 4)))
                    = o[tm][tn][r] * rsum[tm][r];
            }
    __syncthreads();   // B6

    for (int it = 0; it < 8; ++it) {
        int f4i = it * 256 + tid;
        int c = f4i >> 4, t4 = f4i & 15;
        float4 v = *(const float4*)(sOut + c * 256 + ((t4 * 16) ^ ((c & 7) << 4)));
        *(float4*)(out + xbase + (long)c * 16384 + t4 * 4) = v;
    }
}

extern "C" void kernel_launch(void* const* d_in, const int* in_sizes, int n_in,
                              void* d_out, int out_size, void* d_ws, size_t ws_size,
                              hipStream_t stream) {
    const float* x  = (const float*)d_in[0];
    const float* Wq = (const float*)d_in[1];
    const float* bq = (const float*)d_in[2];
    const float* Wk = (const float*)d_in[3];
    const float* bk = (const float*)d_in[4];
    const float* Wv = (const float*)d_in[5];
    const float* bv = (const float*)d_in[6];
    const float* Bb = (const float*)d_in[7];
    float* out = (float*)d_out;
    ushort* wbf = (ushort*)d_ws;   // 3 x 128x128 bf16 = 96 KB

    wconv<<<64, 256, 0, stream>>>(Wq, Wk, Wv, wbf);
    attn_win<<<4096, 256, 0, stream>>>(x, wbf, bq, bk, bv, Bb, out);
}

// Round 2
// 151.958 us; speedup vs baseline: 1.3539x; 1.3539x over previous
//
#include <hip/hip_runtime.h>

// Windowed MHA, B=16 C=128 H=W=128, WINDOW=64, heads=4, d=32.
// One block per (batch, window): 4096 blocks x 512 threads (8 waves).
// Wave = (head w, token-half h): handles 32 q-tokens of head w.
// bf16 MFMA 16x16x32, fp32 accumulate. LDS tiles XOR-swizzled.

typedef __attribute__((ext_vector_type(8))) short bf16x8;
typedef __attribute__((ext_vector_type(4))) float f32x4;

__device__ __forceinline__ ushort f2bf(float f) {
    unsigned u = __float_as_uint(f);
    u += 0x7FFF + ((u >> 16) & 1);          // RNE
    return (ushort)(u >> 16);
}

__global__ void wconv(const float* __restrict__ Wq, const float* __restrict__ Wk,
                      const float* __restrict__ Wv, ushort* __restrict__ out) {
    int i = blockIdx.x * 256 + threadIdx.x;        // 16384 per matrix
    out[i]         = f2bf(Wq[i]);
    out[16384 + i] = f2bf(Wk[i]);
    out[32768 + i] = f2bf(Wv[i]);
}

__global__ __launch_bounds__(512, 4)
void attn_win(const float* __restrict__ x, const ushort* __restrict__ wbf,
              const float* __restrict__ bq, const float* __restrict__ bk,
              const float* __restrict__ bv, const float* __restrict__ Bb,
              float* __restrict__ out) {
    __shared__ __align__(16) char smem[65536];
    // [0,16K) sX   [16K,32K) sQ   [32K,48K) sK   [48K,64K) sVt
    // sP (4 heads x 8K) aliases [16K,48K) after B3.
    char* sX  = smem;
    char* sQ  = smem + 16384;
    char* sK  = smem + 32768;
    char* sVt = smem + 49152;
    char* sP  = smem + 16384;

    const int tid = threadIdx.x;
    const int wid = tid >> 6;        // 0..7
    const int w = wid & 3;           // head
    const int h = wid >> 2;          // token half (0..1)
    const int l = tid & 63;
    const int lr = l & 15;
    const int lg = (l >> 4) & 3;
    const int blk = blockIdx.x;
    const int b = blk >> 8, n = blk & 255;
    const long xbase = (long)b * 128 * 16384 + n * 64;

    // ---- stage X window (64 tok x 128 ch) fp32 -> bf16 sX[t][c], swizzled ----
    #pragma unroll
    for (int it = 0; it < 4; ++it) {
        int f4i = it * 512 + tid;            // 2048 float4 total
        int c = f4i >> 4, t4 = f4i & 15;
        float4 v = *(const float4*)(x + xbase + (long)c * 16384 + t4 * 4);
        float vv[4] = {v.x, v.y, v.z, v.w};
        #pragma unroll
        for (int jj = 0; jj < 4; ++jj) {
            int t = t4 * 4 + jj;
            *(ushort*)(sX + t * 256 + ((c * 2) ^ ((t & 7) << 4))) = f2bf(vv[jj]);
        }
    }
    __syncthreads();   // B1

    // ---- A-fragments of X for this wave's 32 tokens ----
    bf16x8 aX[2][4];
    #pragma unroll
    for (int tmi = 0; tmi < 2; ++tmi) {
        int row = 32 * h + 16 * tmi + lr;
        #pragma unroll
        for (int kk = 0; kk < 4; ++kk) {
            int colb = (8 * lg + 32 * kk) * 2;
            aX[tmi][kk] = *(const bf16x8*)(sX + row * 256 + (colb ^ ((row & 7) << 4)));
        }
    }

    // ---- projections: wave computes tokens 32h..+31, out-ch 32w..+31 ----
    const float* biases[3] = {bq, bk, bv};
    #pragma unroll
    for (int p = 0; p < 3; ++p) {
        const ushort* wp = wbf + p * 16384;
        bf16x8 bW[2][4];
        #pragma unroll
        for (int tn = 0; tn < 2; ++tn) {
            int orow = 32 * w + 16 * tn + lr;
            #pragma unroll
            for (int kk = 0; kk < 4; ++kk)
                bW[tn][kk] = *(const bf16x8*)(wp + orow * 128 + 8 * lg + 32 * kk);
        }
        f32x4 acc[2][2];
        #pragma unroll
        for (int tn = 0; tn < 2; ++tn) {
            float bias = biases[p][32 * w + 16 * tn + lr];
            #pragma unroll
            for (int tmi = 0; tmi < 2; ++tmi)
                acc[tmi][tn] = (f32x4){bias, bias, bias, bias};
        }
        #pragma unroll
        for (int kk = 0; kk < 4; ++kk)
            #pragma unroll
            for (int tmi = 0; tmi < 2; ++tmi)
                #pragma unroll
                for (int tn = 0; tn < 2; ++tn)
                    acc[tmi][tn] = __builtin_amdgcn_mfma_f32_16x16x32_bf16(
                        aX[tmi][kk], bW[tn][kk], acc[tmi][tn], 0, 0, 0);
        if (p < 2) {
            char* dst = (p == 0) ? sQ : sK;
            #pragma unroll
            for (int tmi = 0; tmi < 2; ++tmi)
                #pragma unroll
                for (int tn = 0; tn < 2; ++tn)
                    #pragma unroll
                    for (int r = 0; r < 4; ++r) {
                        int row = 32 * h + 16 * tmi + 4 * lg + r;
                        int col = 32 * w + 16 * tn + lr;
                        *(ushort*)(dst + row * 256 + ((col * 2) ^ ((row & 7) << 4)))
                            = f2bf(acc[tmi][tn][r]);
                    }
        } else {
            // V transposed: sVt[c][token], rowbytes 128
            #pragma unroll
            for (int tmi = 0; tmi < 2; ++tmi)
                #pragma unroll
                for (int tn = 0; tn < 2; ++tn)
                    #pragma unroll
                    for (int r = 0; r < 4; ++r) {
                        int crow = 32 * w + 16 * tn + lr;
                        int tok = 32 * h + 16 * tmi + 4 * lg + r;
                        *(ushort*)(sVt + crow * 128 + ((tok * 2) ^ ((crow & 7) << 4)))
                            = f2bf(acc[tmi][tn][r]);
                    }
        }
    }
    __syncthreads();   // B2

    // ---- scores: q = 32h..+31 (2 tiles), k = all 64 (4 tiles), K-dim = 32 ----
    bf16x8 aQ[2], bK[4];
    #pragma unroll
    for (int tmi = 0; tmi < 2; ++tmi) {
        int row = 32 * h + 16 * tmi + lr;
        int colb = (32 * w + 8 * lg) * 2;
        aQ[tmi] = *(const bf16x8*)(sQ + row * 256 + (colb ^ ((row & 7) << 4)));
    }
    #pragma unroll
    for (int tn = 0; tn < 4; ++tn) {
        int tok = 16 * tn + lr;
        int colb = (32 * w + 8 * lg) * 2;
        bK[tn] = *(const bf16x8*)(sK + tok * 256 + (colb ^ ((tok & 7) << 4)));
    }
    f32x4 sc[2][4];
    #pragma unroll
    for (int tmi = 0; tmi < 2; ++tmi)
        #pragma unroll
        for (int tn = 0; tn < 4; ++tn) {
            sc[tmi][tn] = (f32x4){0.f, 0.f, 0.f, 0.f};
            sc[tmi][tn] = __builtin_amdgcn_mfma_f32_16x16x32_bf16(
                aQ[tmi], bK[tn], sc[tmi][tn], 0, 0, 0);
        }

    // ---- softmax in registers. q-row = 32h+16tmi+4lg+r spans lanes lr x tn ----
    const float scale = 0.17677669529663687f;   // 1/sqrt(32)
    #pragma unroll
    for (int tmi = 0; tmi < 2; ++tmi)
        #pragma unroll
        for (int tn = 0; tn < 4; ++tn)
            #pragma unroll
            for (int r = 0; r < 4; ++r) {
                int q = 32 * h + 16 * tmi + 4 * lg + r;
                int k = 16 * tn + lr;
                sc[tmi][tn][r] = sc[tmi][tn][r] * scale + Bb[q * 64 + k];
            }
    float rsum[2][4];
    #pragma unroll
    for (int tmi = 0; tmi < 2; ++tmi)
        #pragma unroll
        for (int r = 0; r < 4; ++r) {
            float m = fmaxf(fmaxf(sc[tmi][0][r], sc[tmi][1][r]),
                            fmaxf(sc[tmi][2][r], sc[tmi][3][r]));
            m = fmaxf(m, __shfl_xor(m, 1));
            m = fmaxf(m, __shfl_xor(m, 2));
            m = fmaxf(m, __shfl_xor(m, 4));
            m = fmaxf(m, __shfl_xor(m, 8));
            float s = 0.f;
            #pragma unroll
            for (int tn = 0; tn < 4; ++tn) {
                float e = exp2f((sc[tmi][tn][r] - m) * 1.4426950408889634f);
                sc[tmi][tn][r] = e;
                s += e;
            }
            s += __shfl_xor(s, 1);
            s += __shfl_xor(s, 2);
            s += __shfl_xor(s, 4);
            s += __shfl_xor(s, 8);
            rsum[tmi][r] = 1.0f / s;
        }
    __syncthreads();   // B3: sQ/sK reads done before sP overwrite

    // ---- write probs bf16 to per-head sP [64][64] (waves h=0/1 disjoint rows) ----
    char* sPw = sP + w * 8192;
    #pragma unroll
    for (int tmi = 0; tmi < 2; ++tmi)
        #pragma unroll
        for (int tn = 0; tn < 4; ++tn)
            #pragma unroll
            for (int r = 0; r < 4; ++r) {
                int q = 32 * h + 16 * tmi + 4 * lg + r;
                int k = 16 * tn + lr;
                *(ushort*)(sPw + q * 128 + ((k * 2) ^ ((q & 7) << 4))) = f2bf(sc[tmi][tn][r]);
            }
    __syncthreads();   // B4

    // ---- out = P . V : q 32 rows (2 tiles), d 32 (2 tiles), K = 64 keys ----
    f32x4 o[2][2];
    #pragma unroll
    for (int tmi = 0; tmi < 2; ++tmi)
        #pragma unroll
        for (int tn = 0; tn < 2; ++tn)
            o[tmi][tn] = (f32x4){0.f, 0.f, 0.f, 0.f};
    #pragma unroll
    for (int kk = 0; kk < 2; ++kk) {
        bf16x8 aP[2], bV[2];
        #pragma unroll
        for (int tmi = 0; tmi < 2; ++tmi) {
            int q = 32 * h + 16 * tmi + lr;
            int colb = (32 * kk + 8 * lg) * 2;
            aP[tmi] = *(const bf16x8*)(sPw + q * 128 + (colb ^ ((q & 7) << 4)));
        }
        #pragma unroll
        for (int tn = 0; tn < 2; ++tn) {
            int cc = 32 * w + 16 * tn + lr;
            int colb = (32 * kk + 8 * lg) * 2;
            bV[tn] = *(const bf16x8*)(sVt + cc * 128 + (colb ^ ((cc & 7) << 4)));
        }
        #pragma unroll
        for (int tmi = 0; tmi < 2; ++tmi)
            #pragma unroll
            for (int tn = 0; tn < 2; ++tn)
                o[tmi][tn] = __builtin_amdgcn_mfma_f32_16x16x32_bf16(
                    aP[tmi], bV[tn], o[tmi][tn], 0, 0, 0);
    }

    // ---- normalize + direct coalesced float4 stores (4 consecutive tokens/reg) ----
    #pragma unroll
    for (int tmi = 0; tmi < 2; ++tmi)
        #pragma unroll
        for (int tn = 0; tn < 2; ++tn) {
            int ch = 32 * w + 16 * tn + lr;
            int tok = 32 * h + 16 * tmi + 4 * lg;
            float4 ov;
            ov.x = o[tmi][tn][0] * rsum[tmi][0];
            ov.y = o[tmi][tn][1] * rsum[tmi][1];
            ov.z = o[tmi][tn][2] * rsum[tmi][2];
            ov.w = o[tmi][tn][3] * rsum[tmi][3];
            *(float4*)(out + xbase + (long)ch * 16384 + tok) = ov;
        }
}

extern "C" void kernel_launch(void* const* d_in, const int* in_sizes, int n_in,
                              void* d_out, int out_size, void* d_ws, size_t ws_size,
                              hipStream_t stream) {
    const float* x  = (const float*)d_in[0];
    const float* Wq = (const float*)d_in[1];
    const float* bq = (const float*)d_in[2];
    const float* Wk = (const float*)d_in[3];
    const float* bk = (const float*)d_in[4];
    const float* Wv = (const float*)d_in[5];
    const float* bv = (const float*)d_in[6];
    const float* Bb = (const float*)d_in[7];
    float* out = (float*)d_out;
    ushort* wbf = (ushort*)d_ws;   // 3 x 128x128 bf16 = 96 KB

    wconv<<<64, 256, 0, stream>>>(Wq, Wk, Wv, wbf);
    attn_win<<<4096, 512, 0, stream>>>(x, wbf, bq, bk, bv, Bb, out);
}